// Round 15
// baseline (6176.605 us; speedup 1.0000x reference)
//
#include <hip/hip_runtime.h>
#include <hip/hip_bf16.h>

#define LSEQ 1024

typedef __attribute__((ext_vector_type(8))) short short8;
typedef __attribute__((ext_vector_type(4))) float f32x4;
typedef __attribute__((ext_vector_type(4))) unsigned short us4;

static __device__ __forceinline__ short f2bf(float f) {
    unsigned u = __builtin_bit_cast(unsigned, f);
    u += 0x7fffu + ((u >> 16) & 1u);
    return (short)(u >> 16);
}
static __device__ __forceinline__ float bf2f(unsigned short s) {
    unsigned u = ((unsigned)s) << 16;
    return __builtin_bit_cast(float, u);
}
static __device__ __forceinline__ float sigm(float x) { return __fdividef(1.f, 1.f + __expf(-x)); }
static __device__ __forceinline__ float tanh2(float g) { return 1.f - 2.f * __fdividef(1.f, 1.f + __expf(g)); }

static __device__ __forceinline__ void st64g(unsigned long long* p, unsigned long long v) { __hip_atomic_store(p, v, __ATOMIC_RELAXED, __HIP_MEMORY_SCOPE_AGENT); }
static __device__ __forceinline__ unsigned long long ld64g(const unsigned long long* p) { return __hip_atomic_load(p, __ATOMIC_RELAXED, __HIP_MEMORY_SCOPE_AGENT); }

// ============ PHASE 1: Gx[t] = x_t @ Wx + b  (R14-verbatim) ============
extern "C" __global__ void __launch_bounds__(512)
gx_kernel(const float* __restrict__ x,
          const float* __restrict__ Wi, const float* __restrict__ bi,
          const float* __restrict__ Wf, const float* __restrict__ bf,
          const float* __restrict__ Wie, const float* __restrict__ bie,
          const float* __restrict__ Wfe, const float* __restrict__ bfe,
          const float* __restrict__ Wz, const float* __restrict__ bz,
          const float* __restrict__ Wo, const float* __restrict__ bo,
          const float* __restrict__ Wd, const float* __restrict__ bdp,
          unsigned short* __restrict__ ringbf, int t0, int spb)
{
    const int tid  = threadIdx.x;
    const int w    = tid >> 6;
    const int lane = tid & 63;
    const int l16  = lane & 15;
    const int lhi  = lane >> 4;

    const int p  = blockIdx.x & 15;
    const int sl = blockIdx.x >> 4;
    const int g  = p & 3;
    const int qt = p >> 2;
    const int base_ct = qt * 24 + w * 3;
    const int nt = (qt == 3 && w == 7) ? 4 : 3;

    short8 wx[4][8];
    f32x4 bias[4];
    #pragma unroll
    for (int i = 0; i < 4; ++i) {
        if (i < nt) {
            const int ct = base_ct + i;
            if (ct == 96) {
                const float bv = (l16 == 0) ? bdp[0] : 0.f;
                bias[i] = f32x4{bv, bv, bv, bv};
                #pragma unroll
                for (int kk = 0; kk < 8; ++kk) {
                    short8 f;
                    #pragma unroll
                    for (int e = 0; e < 8; ++e)
                        f[e] = (l16 == 0) ? f2bf(Wd[kk * 32 + lhi * 8 + e]) : (short)0;
                    wx[i][kk] = f;
                }
            } else {
                const int gt = ct >> 4, jtg = ct & 15;
                const float* Wg; const float* bg;
                switch (gt) {
                    case 0: Wg = Wi;  bg = bi;  break;
                    case 1: Wg = Wf;  bg = bf;  break;
                    case 2: Wg = Wie; bg = bie; break;
                    case 3: Wg = Wfe; bg = bfe; break;
                    case 4: Wg = Wz;  bg = bz;  break;
                    default: Wg = Wo; bg = bo;  break;
                }
                const int col = jtg * 16 + l16;
                const float bv = bg[col];
                bias[i] = f32x4{bv, bv, bv, bv};
                #pragma unroll
                for (int kk = 0; kk < 8; ++kk) {
                    short8 f;
                    #pragma unroll
                    for (int e = 0; e < 8; ++e)
                        f[e] = f2bf(Wg[(kk * 32 + lhi * 8 + e) * 256 + col]);
                    wx[i][kk] = f;
                }
            }
        }
    }

    const size_t xb = (size_t)(g * 16 + l16) * LSEQ;
    const int tb = t0 + sl * spb;
    for (int ti = 0; ti < spb; ++ti) {
        const int t = tb + ti;
        const float* xp = x + (xb + t) * 256;
        short8 af[8];
        #pragma unroll
        for (int kk = 0; kk < 8; ++kk) {
            const f32x4 a  = *(const f32x4*)(xp + kk * 32 + lhi * 8);
            const f32x4 b2 = *(const f32x4*)(xp + kk * 32 + lhi * 8 + 4);
            short8 f;
            #pragma unroll
            for (int e = 0; e < 4; ++e) { f[e] = f2bf(a[e]); f[4 + e] = f2bf(b2[e]); }
            af[kk] = f;
        }
        f32x4 acc[4];
        #pragma unroll
        for (int i = 0; i < 4; ++i)
            if (i < nt) acc[i] = bias[i];
        #pragma unroll
        for (int kk = 0; kk < 8; ++kk) {
            #pragma unroll
            for (int i = 0; i < 4; ++i)
                if (i < nt)
                    acc[i] = __builtin_amdgcn_mfma_f32_16x16x32_bf16(af[kk], wx[i][kk], acc[i], 0, 0, 0);
        }
        #pragma unroll
        for (int i = 0; i < 4; ++i) {
            if (i < nt) {
                us4 o;
                #pragma unroll
                for (int e = 0; e < 4; ++e) o[e] = (unsigned short)f2bf(acc[i][e]);
                us4* pp = (us4*)&ringbf[(((size_t)(t - t0) * 4 + g) * 97 + base_ct + i) * 256 + lane * 4];
                *pp = o;   // plain cacheable store
            }
        }
    }
}

// ============ PHASE 2: recurrence, ROLE-SPLIT waves ============
// waves 4-7: full U (2 items/thread) with publish-FIRST; waves 1-3: poll
// peers concurrently (start at bar1, overlap with U); wave 0: delta head.
extern "C" __global__ void __launch_bounds__(512)
__attribute__((amdgpu_waves_per_eu(2, 2)))
rec_kernel(const float* __restrict__ td,
           const float* __restrict__ Wi, const float* __restrict__ Wf,
           const float* __restrict__ Wie, const float* __restrict__ Wfe,
           const float* __restrict__ Wz, const float* __restrict__ Wo,
           const float* __restrict__ Wd, const float* __restrict__ betap,
           float* __restrict__ out, char* __restrict__ hbuf,
           const unsigned short* __restrict__ ringbf, char* __restrict__ stbuf,
           int t0, int t1)
{
    const int tid  = threadIdx.x;
    const int w    = tid >> 6;
    const int lane = tid & 63;
    const int l16  = lane & 15;
    const int lhi  = lane >> 4;

    const int g = blockIdx.x >> 2;
    const int c = blockIdx.x & 3;

    __shared__ float g_lds[24][17][18];
    __shared__ __align__(16) unsigned short h_lds[2 * 16 * 256];
    __shared__ float dvals[16];
    __shared__ float wd_lds[256];

    if (tid < 256) wd_lds[tid] = Wd[256 + tid];

    char* myst = stbuf + (size_t)blockIdx.x * 32768;
    if (t0 == 0) {
        #pragma unroll
        for (int i = 0; i < 4; ++i) ((unsigned long long*)h_lds)[tid + i * 512] = 0ull;
    } else {
        unsigned long long* dz = (unsigned long long*)((char*)h_lds + (t0 & 1) * 8192);
        const unsigned long long* sz = (const unsigned long long*)myst;
        dz[tid] = sz[tid];
        dz[tid + 512] = sz[tid + 512];
    }

    const float beta = betap[0];

    // resident gate weights (h-part rows 256..511): 3 tiles/wave
    short8 wfrag[3][8];
    #pragma unroll
    for (int i = 0; i < 3; ++i) {
        const int T = w * 3 + i, gt = T >> 2, jt = T & 3;
        const float* Wg;
        switch (gt) {
            case 0: Wg = Wi;  break;
            case 1: Wg = Wf;  break;
            case 2: Wg = Wie; break;
            case 3: Wg = Wfe; break;
            case 4: Wg = Wz;  break;
            default: Wg = Wo; break;
        }
        const int col = c * 64 + jt * 16 + l16;
        #pragma unroll
        for (int kk = 0; kk < 8; ++kk) {
            short8 f;
            #pragma unroll
            for (int e = 0; e < 8; ++e)
                f[e] = f2bf(Wg[(256 + kk * 32 + lhi * 8 + e) * 256 + col]);
            wfrag[i][kk] = f;
        }
    }

    // publisher state (waves 4-7): 2 items/thread: idx = u2, u2+256
    const int u2 = tid & 255;
    float cC[2][2], ceS[2][2], h2[2][2];
    if (w >= 4) {
        if (t0 == 0) {
            #pragma unroll
            for (int it = 0; it < 2; ++it)
                cC[it][0] = cC[it][1] = ceS[it][0] = ceS[it][1] = h2[it][0] = h2[it][1] = 0.f;
        } else {
            const float* fs = (const float*)(myst + 8192) + u2 * 12;
            #pragma unroll
            for (int it = 0; it < 2; ++it) {
                cC[it][0] = fs[it * 6 + 0]; cC[it][1] = fs[it * 6 + 1];
                ceS[it][0] = fs[it * 6 + 2]; ceS[it][1] = fs[it * 6 + 3];
                h2[it][0] = fs[it * 6 + 4]; h2[it][1] = fs[it * 6 + 5];
            }
        }
    }

    int myct[3];
    #pragma unroll
    for (int i = 0; i < 3; ++i) {
        const int T = w * 3 + i;
        myct[i] = (T >> 2) * 16 + c * 4 + (T & 3);
    }

    us4 gxr[3];
    unsigned short gxd = 0;
    auto load_gx = [&](int tl) {
        #pragma unroll
        for (int i = 0; i < 3; ++i)
            gxr[i] = *(const us4*)&ringbf[(((size_t)tl * 4 + g) * 97 + myct[i]) * 256 + lane * 4];
        if (w == 0)
            gxd = ringbf[(((size_t)tl * 4 + g) * 97 + 96) * 256 + (l16 >> 2) * 64 + (l16 & 3)];
    };
    load_gx(0);
    __syncthreads();

    for (int t = t0; t < t1; ++t) {
        const int zone_cur = (t & 1) * 8192;
        const int zone_nxt = ((t + 1) & 1) * 8192;

        // td prefetch for publisher waves (consumed in U)
        float dtv[2];
        if (w >= 4 && t + 1 < LSEQ) {
            #pragma unroll
            for (int it = 0; it < 2; ++it)
                dtv[it] = td[(size_t)(g * 16 + ((u2 + it * 256) >> 5)) * LSEQ + (t + 1)];
        }

        // ---------- phase G (all waves) ----------
        short8 hf[8];
        #pragma unroll
        for (int kk = 0; kk < 8; ++kk) {
            const int bo = zone_cur + l16 * 512 + ((kk * 64 + lhi * 16) ^ ((l16 & 7) << 4));
            hf[kk] = *(const short8*)((const char*)h_lds + bo);
        }
        f32x4 acc[3];
        #pragma unroll
        for (int i = 0; i < 3; ++i)
            acc[i] = f32x4{bf2f(gxr[i][0]), bf2f(gxr[i][1]), bf2f(gxr[i][2]), bf2f(gxr[i][3])};
        #pragma unroll
        for (int kk = 0; kk < 8; ++kk) {
            #pragma unroll
            for (int i = 0; i < 3; ++i)
                acc[i] = __builtin_amdgcn_mfma_f32_16x16x32_bf16(hf[kk], wfrag[i][kk], acc[i], 0, 0, 0);
        }
        #pragma unroll
        for (int i = 0; i < 3; ++i) {
            const int T = w * 3 + i, gt = T >> 2;
            #pragma unroll
            for (int q = 0; q < 4; ++q) {
                float v = acc[i][q];
                v = (gt == 4) ? tanh2(v) : sigm(v);
                g_lds[T][lhi * 4 + q][l16] = v;
            }
        }
        if (w == 0) {   // delta head
            float part = 0.f;
            #pragma unroll
            for (int kb = 0; kb < 8; ++kb) {
                const int bo = zone_cur + l16 * 512 + (((lhi * 64 + kb * 8) * 2) ^ ((l16 & 7) << 4));
                const short8 hv = *(const short8*)((const char*)h_lds + bo);
                #pragma unroll
                for (int e = 0; e < 8; ++e)
                    part += bf2f((unsigned short)hv[e]) * wd_lds[lhi * 64 + kb * 8 + e];
            }
            part += __shfl_xor(part, 16);
            part += __shfl_xor(part, 32);
            const float gd = part + bf2f(gxd);
            const float bg_ = beta * gd;
            const float sp  = fmaxf(bg_, 0.f) + __logf(1.f + __expf(-fabsf(bg_)));
            if (lane < 16) dvals[l16] = __fdividef(sp, beta);
        }
        __syncthreads();   // bar1: gates+dvals ready; gxr consumed

        if (t + 1 < t1) load_gx(t + 1 - t0);   // issue early, consumed next G

        if (w >= 4) {
            // ---------- U (publisher waves): publish-FIRST ----------
            float outh[2][2];
            #pragma unroll
            for (int it = 0; it < 2; ++it) {
                const int idx  = u2 + it * 256;
                const int urow = idx >> 5;
                const int up   = idx & 31;
                const int jtl  = up >> 3;
                const int cc2  = (up & 7) * 2;
                const float2 iv  = *(const float2*)&g_lds[0 * 4 + jtl][urow][cc2];
                const float2 fv  = *(const float2*)&g_lds[1 * 4 + jtl][urow][cc2];
                const float2 iev = *(const float2*)&g_lds[2 * 4 + jtl][urow][cc2];
                const float2 fev = *(const float2*)&g_lds[3 * 4 + jtl][urow][cc2];
                const float2 zv  = *(const float2*)&g_lds[4 * 4 + jtl][urow][cc2];
                const float2 ov  = *(const float2*)&g_lds[5 * 4 + jtl][urow][cc2];
                const float dn = dvals[urow];

                outh[it][0] = h2[it][0]; outh[it][1] = h2[it][1];

                const float cs0 = fv.x * cC[it][0] + iv.x * zv.x;
                const float cs1 = fv.y * cC[it][1] + iv.y * zv.y;
                const float ce0 = fev.x * ceS[it][0] + iev.x * zv.x;
                const float ce1 = fev.y * ceS[it][1] + iev.y * zv.y;

                if (t + 1 < LSEQ) {
                    const float e   = __expf(-dn * dtv[it]);
                    const float cn0 = cs0 + (ce0 - cs0) * e;
                    const float cn1 = cs1 + (ce1 - cs1) * e;
                    const float hv0 = ov.x * tanh2(2.f * cn0);
                    const float hv1 = ov.y * tanh2(2.f * cn1);
                    cC[it][0] = cn0; cC[it][1] = cn1;
                    ceS[it][0] = ce0; ceS[it][1] = ce1;
                    h2[it][0] = hv0; h2[it][1] = hv1;
                    const unsigned short b0 = (unsigned short)f2bf(hv0);
                    const unsigned short b1 = (unsigned short)f2bf(hv1);
                    const unsigned long long rec =
                          (unsigned long long)((t + 1) & 0xffff)
                        | ((unsigned long long)b0 << 16)
                        | ((unsigned long long)b1 << 32);
                    char* sb = hbuf + ((size_t)((((t + 1) & 1) * 4 + g) * 4 + c)) * 4096;
                    st64g((unsigned long long*)(sb + (urow * 32 + up) * 8), rec);  // ASAP
                    const unsigned pk = (unsigned)b0 | ((unsigned)b1 << 16);
                    const int lin = c * 128 + up * 4;
                    *(unsigned*)((char*)h_lds + zone_nxt + urow * 512 + (lin ^ ((urow & 7) << 4))) = pk;
                } else {
                    float* so = out + (size_t)64 * LSEQ * 256 + (size_t)(g * 16 + urow) * 769;
                    const int jj = c * 64 + up * 2;
                    so[jj]           = ov.x; so[jj + 1]       = ov.y;
                    so[256 + jj]     = cs0;  so[256 + jj + 1] = cs1;
                    so[512 + jj]     = ce0;  so[512 + jj + 1] = ce1;
                    if (c == 0 && up == 0) so[768] = dn;
                }
            }
            // out-stores after publishing (fire-and-forget)
            #pragma unroll
            for (int it = 0; it < 2; ++it) {
                const int idx  = u2 + it * 256;
                const int urow = idx >> 5;
                const int up   = idx & 31;
                *(float2*)(out + ((size_t)(g * 16 + urow) * LSEQ + t) * 256 + c * 64 + up * 2)
                    = make_float2(outh[it][0], outh[it][1]);
            }
        } else if (w >= 1) {
            // ---------- P (poller waves): poll peers CONCURRENT with U ----------
            if (t + 1 < LSEQ) {
                const int c2 = (c + w) & 3;
                const unsigned long long seqlo = (unsigned long long)((t + 1) & 0xffff);
                const char* sb = hbuf + ((size_t)((((t + 1) & 1) * 4 + g) * 4 + c2)) * 4096;
                unsigned long long rv[8];
                #pragma unroll
                for (int m = 0; m < 8; ++m)
                    rv[m] = ld64g((const unsigned long long*)(sb + (lane * 8 + m) * 8));
                while (true) {
                    bool bad = false;
                    #pragma unroll
                    for (int m = 0; m < 8; ++m)
                        if ((rv[m] & 0xffffull) != seqlo) bad = true;
                    if (!__any(bad)) break;
                    #pragma unroll
                    for (int m = 0; m < 8; ++m)
                        if ((rv[m] & 0xffffull) != seqlo)
                            rv[m] = ld64g((const unsigned long long*)(sb + (lane * 8 + m) * 8));
                }
                #pragma unroll
                for (int m = 0; m < 8; ++m) {
                    const int idx = lane * 8 + m;
                    const int row = idx >> 5;
                    const int rcc = idx & 31;
                    const unsigned val = (unsigned)(rv[m] >> 16);
                    const int lin = c2 * 128 + rcc * 4;
                    *(unsigned*)((char*)h_lds + zone_nxt + row * 512
                                 + (lin ^ ((row & 7) << 4))) = val;
                }
            }
        }
        __syncthreads();   // bar3: h(t+1) fully in LDS
    }

    // chunk-boundary state save
    if (t1 < LSEQ) {
        unsigned long long* dz = (unsigned long long*)myst;
        const unsigned long long* sz = (const unsigned long long*)((char*)h_lds + (t1 & 1) * 8192);
        dz[tid] = sz[tid];
        dz[tid + 512] = sz[tid + 512];
        if (w >= 4) {
            float* fs = (float*)(myst + 8192) + u2 * 12;
            #pragma unroll
            for (int it = 0; it < 2; ++it) {
                fs[it * 6 + 0] = cC[it][0]; fs[it * 6 + 1] = cC[it][1];
                fs[it * 6 + 2] = ceS[it][0]; fs[it * 6 + 3] = ceS[it][1];
                fs[it * 6 + 4] = h2[it][0]; fs[it * 6 + 5] = h2[it][1];
            }
        }
    }
}

extern "C" void kernel_launch(void* const* d_in, const int* in_sizes, int n_in,
                              void* d_out, int out_size, void* d_ws, size_t ws_size,
                              hipStream_t stream) {
    const float* x   = (const float*)d_in[0];
    const float* td  = (const float*)d_in[1];
    const float* Wi  = (const float*)d_in[2];
    const float* bi  = (const float*)d_in[3];
    const float* Wf  = (const float*)d_in[4];
    const float* bf  = (const float*)d_in[5];
    const float* Wie = (const float*)d_in[6];
    const float* bie = (const float*)d_in[7];
    const float* Wfe = (const float*)d_in[8];
    const float* bfe = (const float*)d_in[9];
    const float* Wz  = (const float*)d_in[10];
    const float* bz  = (const float*)d_in[11];
    const float* Wo  = (const float*)d_in[12];
    const float* bo  = (const float*)d_in[13];
    const float* Wd  = (const float*)d_in[14];
    const float* bd  = (const float*)d_in[15];
    const float* be  = (const float*)d_in[16];

    char* hbuf  = (char*)d_ws;                       // 128 KB records (memset)
    char* stbuf = (char*)d_ws + 131072;              // 512 KB chunk state
    unsigned short* ringbf = (unsigned short*)((char*)d_ws + 655360);

    const size_t perstep = (size_t)4 * 97 * 256 * 2;
    int chunk = 64;   // ringbf 12.4 MB: L3-resident
    while (chunk > 16 && ws_size < 655360 + (size_t)chunk * perstep) chunk >>= 1;

    hipMemsetAsync(d_ws, 0, 131072, stream);
    for (int t0 = 0; t0 < LSEQ; t0 += chunk) {
        hipLaunchKernelGGL(gx_kernel, dim3(128), dim3(512), 0, stream,
                           x, Wi, bi, Wf, bf, Wie, bie, Wfe, bfe, Wz, bz, Wo, bo,
                           Wd, bd, ringbf, t0, chunk >> 3);
        hipLaunchKernelGGL(rec_kernel, dim3(16), dim3(512), 0, stream,
                           td, Wi, Wf, Wie, Wfe, Wz, Wo, Wd, be,
                           (float*)d_out, hbuf, ringbf, stbuf, t0, t0 + chunk);
    }
}

// Round 16
// 4956.379 us; speedup vs baseline: 1.2462x; 1.2462x over previous
//
#include <hip/hip_runtime.h>
#include <hip/hip_bf16.h>

#define LSEQ 1024

typedef __attribute__((ext_vector_type(8))) short short8;
typedef __attribute__((ext_vector_type(4))) float f32x4;
typedef __attribute__((ext_vector_type(4))) unsigned short us4;

static __device__ __forceinline__ short f2bf(float f) {
    unsigned u = __builtin_bit_cast(unsigned, f);
    u += 0x7fffu + ((u >> 16) & 1u);
    return (short)(u >> 16);
}
static __device__ __forceinline__ float bf2f(unsigned short s) {
    unsigned u = ((unsigned)s) << 16;
    return __builtin_bit_cast(float, u);
}
static __device__ __forceinline__ float sigm(float x) { return __fdividef(1.f, 1.f + __expf(-x)); }
static __device__ __forceinline__ float tanh2(float g) { return 1.f - 2.f * __fdividef(1.f, 1.f + __expf(g)); }

static __device__ __forceinline__ void st32f(int* p, int v) { __hip_atomic_store(p, v, __ATOMIC_RELAXED, __HIP_MEMORY_SCOPE_AGENT); }
static __device__ __forceinline__ int  ld32f(const int* p) { return __hip_atomic_load(p, __ATOMIC_RELAXED, __HIP_MEMORY_SCOPE_AGENT); }
static __device__ __forceinline__ void st64g(unsigned long long* p, unsigned long long v) { __hip_atomic_store(p, v, __ATOMIC_RELAXED, __HIP_MEMORY_SCOPE_AGENT); }
static __device__ __forceinline__ unsigned long long ld64g(const unsigned long long* p) { return __hip_atomic_load(p, __ATOMIC_RELAXED, __HIP_MEMORY_SCOPE_AGENT); }

// sc0 (L1-bypass, L2-coherent-within-XCD) primitives — used ONLY when the
// group's 4 blocks verified same-XCD residency via the behavioral handshake.
static __device__ __forceinline__ void st64_sc0(unsigned long long* p, unsigned long long v) {
    asm volatile("global_store_dwordx2 %0, %1, off sc0" :: "v"(p), "v"(v) : "memory");
}
static __device__ __forceinline__ void st32_sc0(int* p, int v) {
    asm volatile("global_store_dword %0, %1, off sc0" :: "v"(p), "v"(v) : "memory");
}
static __device__ __forceinline__ int ld32_sc0(const int* p) {
    int r;
    asm volatile("global_load_dword %0, %1, off sc0\n\ts_waitcnt vmcnt(0)"
                 : "=&v"(r) : "v"(p) : "memory");
    return r;
}

// ============ PHASE 1: Gx[t] = x_t @ Wx + b  (R14-verbatim body) ============
extern "C" __global__ void __launch_bounds__(512)
gx_kernel(const float* __restrict__ x,
          const float* __restrict__ Wi, const float* __restrict__ bi,
          const float* __restrict__ Wf, const float* __restrict__ bf,
          const float* __restrict__ Wie, const float* __restrict__ bie,
          const float* __restrict__ Wfe, const float* __restrict__ bfe,
          const float* __restrict__ Wz, const float* __restrict__ bz,
          const float* __restrict__ Wo, const float* __restrict__ bo,
          const float* __restrict__ Wd, const float* __restrict__ bdp,
          unsigned short* __restrict__ ringbf, int t0, int spb)
{
    const int tid  = threadIdx.x;
    const int w    = tid >> 6;
    const int lane = tid & 63;
    const int l16  = lane & 15;
    const int lhi  = lane >> 4;

    const int p  = blockIdx.x & 15;
    const int sl = blockIdx.x >> 4;      // t-slice 0..15
    const int g  = p & 3;
    const int qt = p >> 2;
    const int base_ct = qt * 24 + w * 3;
    const int nt = (qt == 3 && w == 7) ? 4 : 3;

    short8 wx[4][8];
    f32x4 bias[4];
    #pragma unroll
    for (int i = 0; i < 4; ++i) {
        if (i < nt) {
            const int ct = base_ct + i;
            if (ct == 96) {
                const float bv = (l16 == 0) ? bdp[0] : 0.f;
                bias[i] = f32x4{bv, bv, bv, bv};
                #pragma unroll
                for (int kk = 0; kk < 8; ++kk) {
                    short8 f;
                    #pragma unroll
                    for (int e = 0; e < 8; ++e)
                        f[e] = (l16 == 0) ? f2bf(Wd[kk * 32 + lhi * 8 + e]) : (short)0;
                    wx[i][kk] = f;
                }
            } else {
                const int gt = ct >> 4, jtg = ct & 15;
                const float* Wg; const float* bg;
                switch (gt) {
                    case 0: Wg = Wi;  bg = bi;  break;
                    case 1: Wg = Wf;  bg = bf;  break;
                    case 2: Wg = Wie; bg = bie; break;
                    case 3: Wg = Wfe; bg = bfe; break;
                    case 4: Wg = Wz;  bg = bz;  break;
                    default: Wg = Wo; bg = bo;  break;
                }
                const int col = jtg * 16 + l16;
                const float bv = bg[col];
                bias[i] = f32x4{bv, bv, bv, bv};
                #pragma unroll
                for (int kk = 0; kk < 8; ++kk) {
                    short8 f;
                    #pragma unroll
                    for (int e = 0; e < 8; ++e)
                        f[e] = f2bf(Wg[(kk * 32 + lhi * 8 + e) * 256 + col]);
                    wx[i][kk] = f;
                }
            }
        }
    }

    const size_t xb = (size_t)(g * 16 + l16) * LSEQ;
    const int tb = t0 + sl * spb;
    for (int ti = 0; ti < spb; ++ti) {
        const int t = tb + ti;
        const float* xp = x + (xb + t) * 256;
        short8 af[8];
        #pragma unroll
        for (int kk = 0; kk < 8; ++kk) {
            const f32x4 a  = *(const f32x4*)(xp + kk * 32 + lhi * 8);
            const f32x4 b2 = *(const f32x4*)(xp + kk * 32 + lhi * 8 + 4);
            short8 f;
            #pragma unroll
            for (int e = 0; e < 4; ++e) { f[e] = f2bf(a[e]); f[4 + e] = f2bf(b2[e]); }
            af[kk] = f;
        }
        f32x4 acc[4];
        #pragma unroll
        for (int i = 0; i < 4; ++i)
            if (i < nt) acc[i] = bias[i];
        #pragma unroll
        for (int kk = 0; kk < 8; ++kk) {
            #pragma unroll
            for (int i = 0; i < 4; ++i)
                if (i < nt)
                    acc[i] = __builtin_amdgcn_mfma_f32_16x16x32_bf16(af[kk], wx[i][kk], acc[i], 0, 0, 0);
        }
        #pragma unroll
        for (int i = 0; i < 4; ++i) {
            if (i < nt) {
                us4 o;
                #pragma unroll
                for (int e = 0; e < 4; ++e) o[e] = (unsigned short)f2bf(acc[i][e]);
                us4* pp = (us4*)&ringbf[(((size_t)(t - t0) * 4 + g) * 97 + base_ct + i) * 256 + lane * 4];
                *pp = o;   // plain cacheable store
            }
        }
    }
}

// ============ PHASE 2: recurrence. h-exchange via same-XCD L2 when verified. ============
// Grid = 32 blocks; active iff (b&7)<4: group g=b&7, slice c=b>>3 ->
// group g's blocks = {g, g+8, g+16, g+24} -> same XCD under round-robin.
extern "C" __global__ void __launch_bounds__(512)
__attribute__((amdgpu_waves_per_eu(2, 2)))
rec_kernel(const float* __restrict__ td,
           const float* __restrict__ Wi, const float* __restrict__ Wf,
           const float* __restrict__ Wie, const float* __restrict__ Wfe,
           const float* __restrict__ Wz, const float* __restrict__ Wo,
           const float* __restrict__ Wd, const float* __restrict__ betap,
           float* __restrict__ out,
           char* __restrict__ hbufL2, char* __restrict__ hbufA,
           char* __restrict__ hs, char* __restrict__ votes,
           const unsigned short* __restrict__ ringbf, char* __restrict__ stbuf,
           int t0, int t1, int epoch)
{
    const int b = blockIdx.x;
    if ((b & 7) >= 4) return;            // placement spacers
    const int g = b & 7;
    const int c = b >> 3;

    const int tid  = threadIdx.x;
    const int w    = tid >> 6;
    const int lane = tid & 63;
    const int l16  = lane & 15;
    const int lhi  = lane >> 4;

    __shared__ float g_lds[24][17][18];
    __shared__ __align__(16) unsigned short h_lds[2 * 16 * 256];
    __shared__ float dvals[16];
    __shared__ float wd_lds[256];
    __shared__ int uni_sh;

    if (tid < 256) wd_lds[tid] = Wd[256 + tid];

    char* myst = stbuf + (size_t)(g * 4 + c) * 32768;
    if (t0 == 0) {
        #pragma unroll
        for (int i = 0; i < 4; ++i) ((unsigned long long*)h_lds)[tid + i * 512] = 0ull;
    } else {
        unsigned long long* dz = (unsigned long long*)((char*)h_lds + (t0 & 1) * 8192);
        const unsigned long long* sz = (const unsigned long long*)myst;
        dz[tid] = sz[tid];
        dz[tid + 512] = sz[tid + 512];
    }

    // ---- behavioral same-XCD handshake (tid 0), 8 rounds, bounded ----
    if (tid == 0) {
        int* my = (int*)(hs + (g * 4 + c) * 128);
        int ok = 1;
        for (int r = 1; r <= 8 && ok; ++r) {
            st32_sc0(my, epoch * 16 + r);
            int seen = 0;
            for (int it = 0; it < 400 && seen < 4; ++it) {
                seen = 0;
                for (int j = 0; j < 4; ++j)
                    seen += (ld32_sc0((const int*)(hs + (g * 4 + j) * 128)) >= epoch * 16 + r);
            }
            if (seen < 4) ok = 0;
        }
        st32f((int*)(votes + (g * 4 + c) * 128), epoch * 4 + (ok ? 2 : 1));
        int mn;
        do {
            mn = 0x7fffffff;
            for (int j = 0; j < 4; ++j) {
                const int v = ld32f((const int*)(votes + (g * 4 + j) * 128));
                if (v < epoch * 4 + 1) { mn = 0; break; }
                if (v < mn) mn = v;
            }
            if (mn == 0) __builtin_amdgcn_s_sleep(4);
        } while (mn == 0);
        uni_sh = (mn == epoch * 4 + 2) ? 1 : 0;   // unanimous yes
    }

    const float beta = betap[0];

    short8 wfrag[3][8];
    #pragma unroll
    for (int i = 0; i < 3; ++i) {
        const int T = w * 3 + i, gt = T >> 2, jt = T & 3;
        const float* Wg;
        switch (gt) {
            case 0: Wg = Wi;  break;
            case 1: Wg = Wf;  break;
            case 2: Wg = Wie; break;
            case 3: Wg = Wfe; break;
            case 4: Wg = Wz;  break;
            default: Wg = Wo; break;
        }
        const int col = c * 64 + jt * 16 + l16;
        #pragma unroll
        for (int kk = 0; kk < 8; ++kk) {
            short8 f;
            #pragma unroll
            for (int e = 0; e < 8; ++e)
                f[e] = f2bf(Wg[(256 + kk * 32 + lhi * 8 + e) * 256 + col]);
            wfrag[i][kk] = f;
        }
    }

    const int urow = tid >> 5;
    const int up   = tid & 31;
    float cC[2], ceS[2], h2[2];
    if (t0 == 0) {
        cC[0] = cC[1] = ceS[0] = ceS[1] = h2[0] = h2[1] = 0.f;
    } else {
        const float* fs = (const float*)(myst + 8192) + tid * 6;
        cC[0] = fs[0]; cC[1] = fs[1]; ceS[0] = fs[2]; ceS[1] = fs[3];
        h2[0] = fs[4]; h2[1] = fs[5];
    }

    int myct[3];
    #pragma unroll
    for (int i = 0; i < 3; ++i) {
        const int T = w * 3 + i;
        myct[i] = (T >> 2) * 16 + c * 4 + (T & 3);
    }

    us4 gxr[3];
    unsigned short gxd = 0;
    auto load_gx = [&](int tl) {
        #pragma unroll
        for (int i = 0; i < 3; ++i)
            gxr[i] = *(const us4*)&ringbf[(((size_t)tl * 4 + g) * 97 + myct[i]) * 256 + lane * 4];
        if (w == 0)
            gxd = ringbf[(((size_t)tl * 4 + g) * 97 + 96) * 256 + (l16 >> 2) * 64 + (l16 & 3)];
    };
    load_gx(0);
    __syncthreads();
    const bool uni = (uni_sh != 0);

    for (int t = t0; t < t1; ++t) {
        const int zone_cur = (t & 1) * 8192;
        const int zone_nxt = ((t + 1) & 1) * 8192;

        // ---------- phase G ----------
        short8 hf[8];
        #pragma unroll
        for (int kk = 0; kk < 8; ++kk) {
            const int bo = zone_cur + l16 * 512 + ((kk * 64 + lhi * 16) ^ ((l16 & 7) << 4));
            hf[kk] = *(const short8*)((const char*)h_lds + bo);
        }
        f32x4 acc[3];
        #pragma unroll
        for (int i = 0; i < 3; ++i)
            acc[i] = f32x4{bf2f(gxr[i][0]), bf2f(gxr[i][1]), bf2f(gxr[i][2]), bf2f(gxr[i][3])};
        #pragma unroll
        for (int kk = 0; kk < 8; ++kk) {
            #pragma unroll
            for (int i = 0; i < 3; ++i)
                acc[i] = __builtin_amdgcn_mfma_f32_16x16x32_bf16(hf[kk], wfrag[i][kk], acc[i], 0, 0, 0);
        }
        #pragma unroll
        for (int i = 0; i < 3; ++i) {
            const int T = w * 3 + i, gt = T >> 2;
            #pragma unroll
            for (int q = 0; q < 4; ++q) {
                float v = acc[i][q];
                v = (gt == 4) ? tanh2(v) : sigm(v);
                g_lds[T][lhi * 4 + q][l16] = v;
            }
        }
        if (w == 0) {   // delta head
            float part = 0.f;
            #pragma unroll
            for (int kb = 0; kb < 8; ++kb) {
                const int bo = zone_cur + l16 * 512 + (((lhi * 64 + kb * 8) * 2) ^ ((l16 & 7) << 4));
                const short8 hv = *(const short8*)((const char*)h_lds + bo);
                #pragma unroll
                for (int e = 0; e < 8; ++e)
                    part += bf2f((unsigned short)hv[e]) * wd_lds[lhi * 64 + kb * 8 + e];
            }
            part += __shfl_xor(part, 16);
            part += __shfl_xor(part, 32);
            const float gd = part + bf2f(gxd);
            const float bg_ = beta * gd;
            const float sp  = fmaxf(bg_, 0.f) + __logf(1.f + __expf(-fabsf(bg_)));
            if (lane < 16) dvals[l16] = __fdividef(sp, beta);
        }
        __syncthreads();   // bar1

        if (t + 1 < t1) load_gx(t + 1 - t0);

        // ---------- phase U ----------
        {
            *(float2*)(out + ((size_t)(g * 16 + urow) * LSEQ + t) * 256 + c * 64 + up * 2)
                = make_float2(h2[0], h2[1]);

            const int jtl = up >> 3;
            const int cc2 = (up & 7) * 2;
            const float2 iv  = *(const float2*)&g_lds[0 * 4 + jtl][urow][cc2];
            const float2 fv  = *(const float2*)&g_lds[1 * 4 + jtl][urow][cc2];
            const float2 iev = *(const float2*)&g_lds[2 * 4 + jtl][urow][cc2];
            const float2 fev = *(const float2*)&g_lds[3 * 4 + jtl][urow][cc2];
            const float2 zv  = *(const float2*)&g_lds[4 * 4 + jtl][urow][cc2];
            const float2 ov  = *(const float2*)&g_lds[5 * 4 + jtl][urow][cc2];
            const float dn = dvals[urow];

            const float cs0 = fv.x * cC[0] + iv.x * zv.x;
            const float cs1 = fv.y * cC[1] + iv.y * zv.y;
            const float ce0 = fev.x * ceS[0] + iev.x * zv.x;
            const float ce1 = fev.y * ceS[1] + iev.y * zv.y;

            if (t + 1 < LSEQ) {
                const float dtv = td[(size_t)(g * 16 + urow) * LSEQ + (t + 1)];
                const float e   = __expf(-dn * dtv);
                const float cn0 = cs0 + (ce0 - cs0) * e;
                const float cn1 = cs1 + (ce1 - cs1) * e;
                const float hv0 = ov.x * tanh2(2.f * cn0);
                const float hv1 = ov.y * tanh2(2.f * cn1);
                cC[0] = cn0; cC[1] = cn1;
                ceS[0] = ce0; ceS[1] = ce1;
                h2[0] = hv0; h2[1] = hv1;
                const unsigned short b0 = (unsigned short)f2bf(hv0);
                const unsigned short b1 = (unsigned short)f2bf(hv1);
                const unsigned long long rec =
                      (unsigned long long)((t + 1) & 0xffff)
                    | ((unsigned long long)b0 << 16)
                    | ((unsigned long long)b1 << 32);
                const size_t so = ((size_t)((((t + 1) & 1) * 4 + g) * 4 + c)) * 4096
                                + (urow * 32 + up) * 8;
                if (uni) {
                    st64_sc0((unsigned long long*)(hbufL2 + so), rec);   // fast L2 path
                    st64g((unsigned long long*)(hbufA + so), rec);       // liveness mirror
                } else {
                    st64g((unsigned long long*)(hbufA + so), rec);
                }
                const unsigned pk = (unsigned)b0 | ((unsigned)b1 << 16);
                const int lin = c * 128 + up * 4;
                *(unsigned*)((char*)h_lds + zone_nxt + urow * 512 + (lin ^ ((urow & 7) << 4))) = pk;
            } else {
                float* so2 = out + (size_t)64 * LSEQ * 256 + (size_t)(g * 16 + urow) * 769;
                const int jj = c * 64 + up * 2;
                so2[jj]           = ov.x; so2[jj + 1]       = ov.y;
                so2[256 + jj]     = cs0;  so2[256 + jj + 1] = cs1;
                so2[512 + jj]     = ce0;  so2[512 + jj + 1] = ce1;
                if (c == 0 && up == 0) so2[768] = dn;
            }
        }

        // ---------- phase P: fetch peer slices ----------
        if (t + 1 < LSEQ) {
            if (w >= 1 && w <= 3) {
                const int c2 = (c + w) & 3;
                const unsigned long long seqlo = (unsigned long long)((t + 1) & 0xffff);
                const size_t so = ((size_t)((((t + 1) & 1) * 4 + g) * 4 + c2)) * 4096
                                + (size_t)lane * 64;
                unsigned long long rv[8];
                bool have = false;
                if (uni) {
                    const unsigned long long* bp = (const unsigned long long*)(hbufL2 + so);
                    for (int rounds = 0; rounds < 4000; ++rounds) {
                        asm volatile(
                            "global_load_dwordx2 %0, %4, off sc0\n\t"
                            "global_load_dwordx2 %1, %5, off sc0\n\t"
                            "global_load_dwordx2 %2, %6, off sc0\n\t"
                            "global_load_dwordx2 %3, %7, off sc0\n\t"
                            "s_waitcnt vmcnt(0)"
                            : "=&v"(rv[0]), "=&v"(rv[1]), "=&v"(rv[2]), "=&v"(rv[3])
                            : "v"(bp), "v"(bp + 1), "v"(bp + 2), "v"(bp + 3)
                            : "memory");
                        asm volatile(
                            "global_load_dwordx2 %0, %4, off sc0\n\t"
                            "global_load_dwordx2 %1, %5, off sc0\n\t"
                            "global_load_dwordx2 %2, %6, off sc0\n\t"
                            "global_load_dwordx2 %3, %7, off sc0\n\t"
                            "s_waitcnt vmcnt(0)"
                            : "=&v"(rv[4]), "=&v"(rv[5]), "=&v"(rv[6]), "=&v"(rv[7])
                            : "v"(bp + 4), "v"(bp + 5), "v"(bp + 6), "v"(bp + 7)
                            : "memory");
                        bool bad = false;
                        #pragma unroll
                        for (int m = 0; m < 8; ++m)
                            if ((rv[m] & 0xffffull) != seqlo) bad = true;
                        if (!__any(bad)) { have = true; break; }
                    }
                }
                if (!have) {   // agent path (guaranteed by mirror / non-uni publish)
                    const unsigned long long* bp = (const unsigned long long*)(hbufA + so);
                    #pragma unroll
                    for (int m = 0; m < 8; ++m) rv[m] = ld64g(bp + m);
                    while (true) {
                        bool bad = false;
                        #pragma unroll
                        for (int m = 0; m < 8; ++m)
                            if ((rv[m] & 0xffffull) != seqlo) bad = true;
                        if (!__any(bad)) break;
                        #pragma unroll
                        for (int m = 0; m < 8; ++m)
                            if ((rv[m] & 0xffffull) != seqlo) rv[m] = ld64g(bp + m);
                    }
                }
                #pragma unroll
                for (int m = 0; m < 8; ++m) {
                    const int idx = lane * 8 + m;
                    const int row = idx >> 5;
                    const int rcc = idx & 31;
                    const unsigned val = (unsigned)(rv[m] >> 16);
                    const int lin = c2 * 128 + rcc * 4;
                    *(unsigned*)((char*)h_lds + zone_nxt + row * 512
                                 + (lin ^ ((row & 7) << 4))) = val;
                }
            }
        }
        __syncthreads();   // bar3
    }

    // chunk-boundary state save (fallback path only)
    if (t1 < LSEQ) {
        unsigned long long* dz = (unsigned long long*)myst;
        const unsigned long long* sz = (const unsigned long long*)((char*)h_lds + (t1 & 1) * 8192);
        dz[tid] = sz[tid];
        dz[tid + 512] = sz[tid + 512];
        float* fs = (float*)(myst + 8192) + tid * 6;
        fs[0] = cC[0]; fs[1] = cC[1]; fs[2] = ceS[0]; fs[3] = ceS[1];
        fs[4] = h2[0]; fs[5] = h2[1];
    }
}

extern "C" void kernel_launch(void* const* d_in, const int* in_sizes, int n_in,
                              void* d_out, int out_size, void* d_ws, size_t ws_size,
                              hipStream_t stream) {
    const float* x   = (const float*)d_in[0];
    const float* td  = (const float*)d_in[1];
    const float* Wi  = (const float*)d_in[2];
    const float* bi  = (const float*)d_in[3];
    const float* Wf  = (const float*)d_in[4];
    const float* bf  = (const float*)d_in[5];
    const float* Wie = (const float*)d_in[6];
    const float* bie = (const float*)d_in[7];
    const float* Wfe = (const float*)d_in[8];
    const float* bfe = (const float*)d_in[9];
    const float* Wz  = (const float*)d_in[10];
    const float* bz  = (const float*)d_in[11];
    const float* Wo  = (const float*)d_in[12];
    const float* bo  = (const float*)d_in[13];
    const float* Wd  = (const float*)d_in[14];
    const float* bd  = (const float*)d_in[15];
    const float* be  = (const float*)d_in[16];

    char* hbufL2 = (char*)d_ws;                       // 128 KB sc0/L2 records
    char* hbufA  = (char*)d_ws + 131072;              // 128 KB agent records
    char* hs     = (char*)d_ws + 262144;              // 2 KB handshake tokens
    char* votes  = (char*)d_ws + 264192;              // 2 KB votes
    char* stbuf  = (char*)d_ws + 266240;              // 512 KB chunk state
    unsigned short* ringbf = (unsigned short*)((char*)d_ws + 790528);

    const size_t perstep = (size_t)4 * 97 * 256 * 2;  // 198656 B
    int chunk = 1024;                                 // single rec launch (R13 ws fits)
    while (chunk > 16 && ws_size < 790528 + (size_t)chunk * perstep) chunk >>= 1;

    hipMemsetAsync(d_ws, 0, 266240, stream);          // replay safety
    int epoch = 1;
    for (int t0 = 0; t0 < LSEQ; t0 += chunk, ++epoch) {
        hipLaunchKernelGGL(gx_kernel, dim3(256), dim3(512), 0, stream,
                           x, Wi, bi, Wf, bf, Wie, bie, Wfe, bfe, Wz, bz, Wo, bo,
                           Wd, bd, ringbf, t0, chunk >> 4);
        hipLaunchKernelGGL(rec_kernel, dim3(32), dim3(512), 0, stream,
                           td, Wi, Wf, Wie, Wfe, Wz, Wo, Wd, be,
                           (float*)d_out, hbufL2, hbufA, hs, votes,
                           ringbf, stbuf, t0, t0 + chunk, epoch);
    }
}